// Round 12
// baseline (710.557 us; speedup 1.0000x reference)
//
#include <hip/hip_runtime.h>
#include <hip/hip_bf16.h>

#define NN 50000
#define NE 500000
#define DCAP 48

using bf16x8 = __attribute__((ext_vector_type(8))) short;
using f32x4  = __attribute__((ext_vector_type(4))) float;

__device__ __forceinline__ float b2f(unsigned short s) {
  union { unsigned u; float f; } v; v.u = ((unsigned)s) << 16; return v.f;
}
__device__ __forceinline__ unsigned short f2b(float f) {
  __hip_bfloat16 h = __float2bfloat16(f);
  return *reinterpret_cast<unsigned short*>(&h);
}
__device__ __forceinline__ unsigned pack2(float a, float b) {
  __hip_bfloat162 h = __float22bfloat162_rn(make_float2(a, b));
  return *reinterpret_cast<unsigned*>(&h);
}
__device__ __forceinline__ float silu_f(float x) {
  return x * __fdividef(1.f, 1.f + __expf(-x));
}

// ---------------- prep: weight repack f32 -> bf16 ----------------
// W1p[528][288]: k<257 = W_e1, k==257 = b_e1 (bias-one trick), else 0
// W2p[64][544]:  K-permuted for 256-col chunks:
//   lk<256 -> h[lk]; lk 256,257 -> h[512,513]; lk==258 -> b_e2;
//   lk 259..287 -> 0; lk>=288 -> h[lk-32]  (i.e. h[256..511])
__global__ void prep_weights(const float* __restrict__ we1,
                             const float* __restrict__ be1,
                             const float* __restrict__ we2,
                             const float* __restrict__ be2,
                             const float* __restrict__ wc1,
                             const float* __restrict__ wn1,
                             const float* __restrict__ wn2,
                             unsigned short* __restrict__ W1p,
                             unsigned short* __restrict__ W2p,
                             unsigned short* __restrict__ Wc1p,
                             unsigned short* __restrict__ Wn1p,
                             unsigned short* __restrict__ Wn2p) {
  int i = blockIdx.x * 256 + threadIdx.x;
  if (i < 152064) {
    int n = i / 288, k = i % 288;
    unsigned short v = 0;
    if (n < 514) {
      if (k < 257) v = f2b(we1[k * 514 + n]);
      else if (k == 257) v = f2b(be1[n]);
    }
    W1p[i] = v;
  } else if (i < 186880) {
    int j = i - 152064; int n = j / 544, lk = j % 544;
    unsigned short v = 0;
    if (lk < 256) v = f2b(we2[lk * 64 + n]);
    else if (lk < 258) v = f2b(we2[(512 + lk - 256) * 64 + n]);
    else if (lk == 258) v = f2b(be2[n]);
    else if (lk >= 288) v = f2b(we2[(lk - 32) * 64 + n]);
    W2p[j] = v;
  } else if (i < 203264) {
    int j = i - 186880; int n = j / 64, k = j % 64;
    Wc1p[j] = f2b(wc1[k * 256 + n]);
  } else if (i < 252416) {
    int j = i - 203264; int n = j / 192, k = j % 192;
    Wn1p[j] = f2b(wn1[k * 256 + n]);
  } else if (i < 285184) {
    int j = i - 252416; int n = j / 256, k = j % 256;
    Wn2p[j] = f2b(wn2[k * 128 + n]);
  }
}

// x(N,131) f32 -> node_p(N,128) bf16 + coords_p(N,4) f32
__global__ void prep_nodes(const float* __restrict__ x,
                           unsigned short* __restrict__ node_p,
                           float* __restrict__ coords_p) {
  int i = blockIdx.x * 256 + threadIdx.x;
  if (i < NN * 16) {
    int g = i >> 4, c = i & 15;
    const float* s = x + g * 131 + c * 8;
    unsigned short* d = node_p + g * 128 + c * 8;
#pragma unroll
    for (int j = 0; j < 8; j++) d[j] = f2b(s[j]);
  } else if (i < NN * 16 + NN) {
    int g = i - NN * 16;
    float4 c;
    c.x = x[g * 131 + 128];
    c.y = x[g * 131 + 129];
    c.z = x[g * 131 + 130];
    c.w = 0.f;
    *(float4*)(coords_p + g * 4) = c;
  }
}

// CSR-lite: per-dst edge list
__global__ void build_adj(const int* __restrict__ eidx,
                          int* __restrict__ cnt, int* __restrict__ adj) {
  int e = blockIdx.x * 256 + threadIdx.x;
  if (e < NE) {
    int d = eidx[NE + e];
    d = min(max(d, 0), NN - 1);
    int slot = atomicAdd(&cnt[d], 1);
    if (slot < DCAP) adj[d * DCAP + slot] = e;
  }
}

// ------------- edge kernel: 48 edges/block, 2x256-col chunks ----------------
// Wider chunks halve sEin A-re-reads (108->54 ds_read_b128/wave) and chunk
// barriers (8->4). LDS 64.9 KB -> 2 blocks/CU (R7 proved 8 waves suffice).
__launch_bounds__(256, 2)
__global__ void edge_kernel(const unsigned short* __restrict__ node_p,
                            const float* __restrict__ coords_p,
                            const int* __restrict__ eidx,
                            const unsigned short* __restrict__ W1p,
                            const unsigned short* __restrict__ W2p,
                            const unsigned short* __restrict__ Wc1p,
                            const float* __restrict__ bc1,
                            const float* __restrict__ bc2,
                            const float* __restrict__ wc2,
                            unsigned short* __restrict__ medge,
                            float* __restrict__ coordw) {
  __shared__ unsigned short sEin[48][296];  // 28,416 B
  __shared__ unsigned short sHc[48][296];   // 28,416 B (ch0: 288 K-cols)
  __shared__ unsigned short sM[48][72];     //  6,912 B
  __shared__ int sDst[48];
  __shared__ int sSrc[48];
  __shared__ float sCwPart[4][48];
  int tid = threadIdx.x, blk = blockIdx.x;
  int lane = tid & 63, wv = tid >> 6, l16 = lane & 15, quad = lane >> 4;

  // ---- phase 0: per-edge scalars (bias-one at k=257) ----
  if (tid < 48) {
    int e = min(blk * 48 + tid, NE - 1);
    int s = eidx[e], d = eidx[NE + e];
    s = min(max(s, 0), NN - 1);
    d = min(max(d, 0), NN - 1);
    float4 cs = *(const float4*)(coords_p + s * 4);
    float4 cd = *(const float4*)(coords_p + d * 4);
    float rx = cs.x - cd.x, ry = cs.y - cd.y, rz = cs.z - cd.z;
    float dist = sqrtf(rx * rx + ry * ry + rz * rz);
    sDst[tid] = d;
    sSrc[tid] = s;
    sEin[tid][256] = f2b(dist);
    sEin[tid][257] = 0x3F80;  // 1.0 bf16 -> bias row of W1p
#pragma unroll
    for (int k = 258; k < 288; k += 2) *(unsigned*)(&sEin[tid][k]) = 0u;
  }
  __syncthreads();
  // ---- gather node features: e_in = [node[dst] | node[src] | dist | 1] ----
#pragma unroll
  for (int it = 0; it < 6; it++) {
    int c = tid + it * 256;
    int row = c >> 5, h = (c >> 4) & 1, off = c & 15;
    int id = h ? sSrc[row] : sDst[row];
    bf16x8 v = *(const bf16x8*)(node_p + id * 128 + off * 8);
    *(bf16x8*)(&sEin[row][h * 128 + off * 8]) = v;
  }
  __syncthreads();

  // ---- fused layer1+layer2 over 2x256-col chunks ----
  f32x4 macc[3];
#pragma unroll
  for (int s = 0; s < 3; s++) macc[s] = (f32x4){0.f, 0.f, 0.f, 0.f};
#pragma unroll 1
  for (int ch = 0; ch < 2; ch++) {
    {  // produce 4 n-tiles per wave (256 h-cols)
      f32x4 acc[4][3];
#pragma unroll
      for (int j = 0; j < 4; j++)
#pragma unroll
        for (int s = 0; s < 3; s++) acc[j][s] = (f32x4){0.f, 0.f, 0.f, 0.f};
      for (int kb = 0; kb < 9; kb++) {
        bf16x8 afr[3], bfr[4];
#pragma unroll
        for (int s = 0; s < 3; s++)
          afr[s] = *(const bf16x8*)(&sEin[s * 16 + l16][kb * 32 + quad * 8]);
#pragma unroll
        for (int j = 0; j < 4; j++)
          bfr[j] = *(const bf16x8*)(W1p + ((ch * 16 + wv * 4 + j) * 16 + l16) * 288 + kb * 32 + quad * 8);
#pragma unroll
        for (int j = 0; j < 4; j++)
#pragma unroll
          for (int s = 0; s < 3; s++)
            acc[j][s] = __builtin_amdgcn_mfma_f32_16x16x32_bf16(bfr[j], afr[s], acc[j][s], 0, 0, 0);
      }
#pragma unroll
      for (int j = 0; j < 4; j++) {
        int lc = (wv * 4 + j) * 16 + quad * 4;
#pragma unroll
        for (int s = 0; s < 3; s++) {
          unsigned lo = pack2(silu_f(acc[j][s][0]), silu_f(acc[j][s][1]));
          unsigned hi = pack2(silu_f(acc[j][s][2]), silu_f(acc[j][s][3]));
          *(uint2*)(&sHc[s * 16 + l16][lc]) = make_uint2(lo, hi);
        }
      }
    }
    if (ch == 0 && wv < 3) {  // tail tile (h 512..513 + bias-one): wave wv -> s=wv
      f32x4 tacc = (f32x4){0.f, 0.f, 0.f, 0.f};
      const unsigned short* wT = W1p + (512 + l16) * 288 + quad * 8;
#pragma unroll
      for (int kb = 0; kb < 9; kb++) {
        bf16x8 a = *(const bf16x8*)(&sEin[wv * 16 + l16][kb * 32 + quad * 8]);
        bf16x8 b = *(const bf16x8*)(wT + kb * 32);
        tacc = __builtin_amdgcn_mfma_f32_16x16x32_bf16(b, a, tacc, 0, 0, 0);
      }
      // K-cols 256..258 = h[512], h[513], bias-one; 259..287 = 0
      unsigned lo, hi;
      if (quad == 0) {
        lo = pack2(silu_f(tacc[0]), silu_f(tacc[1]));
        hi = pack2(1.0f, 0.f);
      } else {
        lo = 0u; hi = 0u;
      }
      *(uint2*)(&sHc[wv * 16 + l16][256 + quad * 4]) = make_uint2(lo, hi);
      *(uint2*)(&sHc[wv * 16 + l16][272 + quad * 4]) = make_uint2(0u, 0u);
    }
    __syncthreads();
    // consume: layer2 partial (bias already inside permuted W2p)
    int nkb = (ch == 0) ? 9 : 8;
    int kof = ch * 288;
    for (int kb = 0; kb < nkb; kb++) {
      bf16x8 b = *(const bf16x8*)(W2p + (wv * 16 + l16) * 544 + kof + kb * 32 + quad * 8);
#pragma unroll
      for (int s = 0; s < 3; s++) {
        bf16x8 a = *(const bf16x8*)(&sHc[s * 16 + l16][kb * 32 + quad * 8]);
        macc[s] = __builtin_amdgcn_mfma_f32_16x16x32_bf16(b, a, macc[s], 0, 0, 0);
      }
    }
    __syncthreads();
  }

  // ---- layer 2 epilogue: m_ij = silu(macc) -> sM ----
  {
    int nb = wv * 16 + quad * 4;
#pragma unroll
    for (int s = 0; s < 3; s++) {
      unsigned lo = pack2(silu_f(macc[s][0]), silu_f(macc[s][1]));
      unsigned hi = pack2(silu_f(macc[s][2]), silu_f(macc[s][3]));
      *(uint2*)(&sM[s * 16 + l16][nb]) = make_uint2(lo, hi);
    }
  }
  __syncthreads();

  // ---- coord head: cw = silu(m @ W_c1 + b_c1) @ W_c2 ----
  {
    float cw[3] = {0.f, 0.f, 0.f};
#pragma unroll
    for (int jt = 0; jt < 4; jt++) {
      int T = wv * 4 + jt;
      f32x4 cacc[3];
#pragma unroll
      for (int s = 0; s < 3; s++) cacc[s] = (f32x4){0.f, 0.f, 0.f, 0.f};
#pragma unroll
      for (int kb = 0; kb < 2; kb++) {
        bf16x8 b = *(const bf16x8*)(Wc1p + (T * 16 + l16) * 64 + kb * 32 + quad * 8);
#pragma unroll
        for (int s = 0; s < 3; s++) {
          bf16x8 a = *(const bf16x8*)(&sM[s * 16 + l16][kb * 32 + quad * 8]);
          cacc[s] = __builtin_amdgcn_mfma_f32_16x16x32_bf16(b, a, cacc[s], 0, 0, 0);
        }
      }
      int nb = T * 16 + quad * 4;
      float4 b4 = *(const float4*)(bc1 + nb);
      float4 w4 = *(const float4*)(wc2 + nb);
#pragma unroll
      for (int s = 0; s < 3; s++) {
        cw[s] += silu_f(cacc[s][0] + b4.x) * w4.x;
        cw[s] += silu_f(cacc[s][1] + b4.y) * w4.y;
        cw[s] += silu_f(cacc[s][2] + b4.z) * w4.z;
        cw[s] += silu_f(cacc[s][3] + b4.w) * w4.w;
      }
    }
#pragma unroll
    for (int s = 0; s < 3; s++) {
      cw[s] += __shfl_xor(cw[s], 16, 64);
      cw[s] += __shfl_xor(cw[s], 32, 64);
    }
    if (quad == 0) {
#pragma unroll
      for (int s = 0; s < 3; s++) sCwPart[wv][s * 16 + l16] = cw[s];
    }
  }
  __syncthreads();
  // ---- stores: m_ij rows (16B/lane) + coord_w scalar ----
#pragma unroll
  for (int it = 0; it < 2; it++) {
    int idx = it * 256 + tid;
    if (idx < 384) {
      int row = idx >> 3, ch8 = idx & 7;
      int e = blk * 48 + row;
      if (e < NE)
        *(bf16x8*)(medge + (size_t)e * 64 + ch8 * 8) = *(const bf16x8*)(&sM[row][ch8 * 8]);
    }
  }
  if (tid < 48) {
    int e = blk * 48 + tid;
    if (e < NE) {
      float v = sCwPart[0][tid] + sCwPart[1][tid] + sCwPart[2][tid] + sCwPart[3][tid]
                + bc2[0];
      coordw[e] = v;
    }
  }
}

// ---- gather kernel: LDS-free, 4 lanes/node, high occupancy ----------------
__global__ void gather_kernel(const float* __restrict__ coords_p,
                              const unsigned short* __restrict__ medge,
                              const float* __restrict__ coordw,
                              const int* __restrict__ eidx,
                              const int* __restrict__ cnt,
                              const int* __restrict__ adj,
                              float* __restrict__ m_i,
                              float* __restrict__ wr) {
  int t = blockIdx.x * 256 + threadIdx.x;
  int g = t >> 2, c = t & 3;
  if (g >= NN) return;
  int deg = min(cnt[g], DCAP);
  float acc[16];
#pragma unroll
  for (int i = 0; i < 16; i++) acc[i] = 0.f;
  float sc = 0.f;
  float cg = (c < 3) ? coords_p[g * 4 + c] : 0.f;
  for (int k = 0; k < deg; k++) {
    int e = adj[g * DCAP + k];
    const unsigned short* mrow = medge + (size_t)e * 64 + c * 16;
    bf16x8 a0 = *(const bf16x8*)(mrow);
    bf16x8 a1 = *(const bf16x8*)(mrow + 8);
#pragma unroll
    for (int i = 0; i < 8; i++) acc[i] += b2f((unsigned short)a0[i]);
#pragma unroll
    for (int i = 0; i < 8; i++) acc[8 + i] += b2f((unsigned short)a1[i]);
    if (c == 3) {
      sc += coordw[e];
    } else {
      int s = eidx[e];
      s = min(max(s, 0), NN - 1);
      sc += coords_p[s * 4 + c] - cg;
    }
  }
  float4* dst = (float4*)(m_i + g * 64 + c * 16);
  dst[0] = make_float4(acc[0], acc[1], acc[2], acc[3]);
  dst[1] = make_float4(acc[4], acc[5], acc[6], acc[7]);
  dst[2] = make_float4(acc[8], acc[9], acc[10], acc[11]);
  dst[3] = make_float4(acc[12], acc[13], acc[14], acc[15]);
  wr[g * 4 + c] = sc;
}

// ---------------- node MLP kernel: pure GEMM, f32 output -------------------
__launch_bounds__(256, 2)
__global__ void node_mlp_kernel(const unsigned short* __restrict__ node_p,
                                const float* __restrict__ x,
                                const float* __restrict__ coords_p,
                                const float* __restrict__ m_i,
                                const float* __restrict__ wr,
                                const unsigned short* __restrict__ Wn1p,
                                const unsigned short* __restrict__ Wn2p,
                                const float* __restrict__ bn1,
                                const float* __restrict__ bn2,
                                float* __restrict__ out) {
  __shared__ unsigned short sNin[64][200];
  __shared__ unsigned short sHid[64][264];
  int tid = threadIdx.x, blk = blockIdx.x;
  int lane = tid & 63, wv = tid >> 6, l16 = lane & 15, quad = lane >> 4;

  // ---- stage n_in = [node | bf16(m_i)] (all coalesced) ----
#pragma unroll
  for (int it = 0; it < 4; it++) {
    int t = tid + it * 256;
    int row = t >> 4, ch = t & 15;
    int g = blk * 64 + row;
    if (g >= NN) g = 0;
    *(bf16x8*)(&sNin[row][ch * 8]) = *(const bf16x8*)(node_p + g * 128 + ch * 8);
  }
#pragma unroll
  for (int it = 0; it < 2; it++) {
    int t = tid + it * 256;
    int row = t >> 3, q = t & 7;
    int g = blk * 64 + row;
    if (g >= NN) g = 0;
    float4 v1 = *(const float4*)(m_i + g * 64 + q * 8);
    float4 v2 = *(const float4*)(m_i + g * 64 + q * 8 + 4);
    unsigned lo1 = pack2(v1.x, v1.y), hi1 = pack2(v1.z, v1.w);
    unsigned lo2 = pack2(v2.x, v2.y), hi2 = pack2(v2.z, v2.w);
    *(uint2*)(&sNin[row][128 + q * 8]) = make_uint2(lo1, hi1);
    *(uint2*)(&sNin[row][128 + q * 8 + 4]) = make_uint2(lo2, hi2);
  }
  __syncthreads();
  // ---- GEMM1: hid = silu(n_in @ W_n1 + b_n1), D^T orientation ----
  {
    f32x4 acc[4][4];
#pragma unroll
    for (int j = 0; j < 4; j++)
#pragma unroll
      for (int s = 0; s < 4; s++) acc[j][s] = (f32x4){0.f, 0.f, 0.f, 0.f};
    for (int kb = 0; kb < 6; kb++) {
      bf16x8 afr[4], bfr[4];
#pragma unroll
      for (int s = 0; s < 4; s++)
        afr[s] = *(const bf16x8*)(&sNin[s * 16 + l16][kb * 32 + quad * 8]);
#pragma unroll
      for (int j = 0; j < 4; j++)
        bfr[j] = *(const bf16x8*)(Wn1p + ((wv * 4 + j) * 16 + l16) * 192 + kb * 32 + quad * 8);
#pragma unroll
      for (int j = 0; j < 4; j++)
#pragma unroll
        for (int s = 0; s < 4; s++)
          acc[j][s] = __builtin_amdgcn_mfma_f32_16x16x32_bf16(bfr[j], afr[s], acc[j][s], 0, 0, 0);
    }
#pragma unroll
    for (int j = 0; j < 4; j++) {
      int nb = (wv * 4 + j) * 16 + quad * 4;
      float4 b4 = *(const float4*)(bn1 + nb);
#pragma unroll
      for (int s = 0; s < 4; s++) {
        unsigned lo = pack2(silu_f(acc[j][s][0] + b4.x), silu_f(acc[j][s][1] + b4.y));
        unsigned hi = pack2(silu_f(acc[j][s][2] + b4.z), silu_f(acc[j][s][3] + b4.w));
        *(uint2*)(&sHid[s * 16 + l16][nb]) = make_uint2(lo, hi);
      }
    }
  }
  __syncthreads();
  // ---- GEMM2: out = hid @ W_n2 + b_n2 + node (f32 residual from x) ----
  {
    f32x4 acc[2][4];
#pragma unroll
    for (int j = 0; j < 2; j++)
#pragma unroll
      for (int s = 0; s < 4; s++) acc[j][s] = (f32x4){0.f, 0.f, 0.f, 0.f};
    for (int kb = 0; kb < 8; kb++) {
      bf16x8 afr[4], bfr[2];
#pragma unroll
      for (int s = 0; s < 4; s++)
        afr[s] = *(const bf16x8*)(&sHid[s * 16 + l16][kb * 32 + quad * 8]);
#pragma unroll
      for (int j = 0; j < 2; j++)
        bfr[j] = *(const bf16x8*)(Wn2p + ((wv * 2 + j) * 16 + l16) * 256 + kb * 32 + quad * 8);
#pragma unroll
      for (int j = 0; j < 2; j++)
#pragma unroll
        for (int s = 0; s < 4; s++)
          acc[j][s] = __builtin_amdgcn_mfma_f32_16x16x32_bf16(bfr[j], afr[s], acc[j][s], 0, 0, 0);
    }
#pragma unroll
    for (int j = 0; j < 2; j++) {
      int nb = (wv * 2 + j) * 16 + quad * 4;
      float4 b4 = *(const float4*)(bn2 + nb);
#pragma unroll
      for (int s = 0; s < 4; s++) {
        int g = blk * 64 + s * 16 + l16;
        if (g < NN) {
          int base = g * 131 + nb;
          out[base + 0] = acc[j][s][0] + b4.x + x[base + 0];
          out[base + 1] = acc[j][s][1] + b4.y + x[base + 1];
          out[base + 2] = acc[j][s][2] + b4.z + x[base + 2];
          out[base + 3] = acc[j][s][3] + b4.w + x[base + 3];
        }
      }
    }
  }
  // ---- coords_out = coords + w_i * r_i ----
  if (tid < 64) {
    int g = blk * 64 + tid;
    if (g < NN) {
      float4 w4 = *(const float4*)(wr + g * 4);
      out[g * 131 + 128] = coords_p[g * 4 + 0] + w4.w * w4.x;
      out[g * 131 + 129] = coords_p[g * 4 + 1] + w4.w * w4.y;
      out[g * 131 + 130] = coords_p[g * 4 + 2] + w4.w * w4.z;
    }
  }
}

extern "C" void kernel_launch(void* const* d_in, const int* in_sizes, int n_in,
                              void* d_out, int out_size, void* d_ws, size_t ws_size,
                              hipStream_t stream) {
  const float* x   = (const float*)d_in[0];
  const int* eidx  = (const int*)d_in[1];
  const float* we1 = (const float*)d_in[2];
  const float* be1 = (const float*)d_in[3];
  const float* we2 = (const float*)d_in[4];
  const float* be2 = (const float*)d_in[5];
  const float* wc1 = (const float*)d_in[6];
  const float* bc1 = (const float*)d_in[7];
  const float* wc2 = (const float*)d_in[8];
  const float* bc2 = (const float*)d_in[9];
  const float* wn1 = (const float*)d_in[10];
  const float* bn1 = (const float*)d_in[11];
  const float* wn2 = (const float*)d_in[12];
  const float* bn2 = (const float*)d_in[13];

  char* ws = (char*)d_ws;
  unsigned short* W1p    = (unsigned short*)(ws + 0);          //    304,128 B
  unsigned short* W2p    = (unsigned short*)(ws + 304128);     //     69,632 B
  unsigned short* Wc1p   = (unsigned short*)(ws + 373760);     //     32,768 B
  unsigned short* Wn1p   = (unsigned short*)(ws + 406528);     //     98,304 B
  unsigned short* Wn2p   = (unsigned short*)(ws + 504832);     //     65,536 B
  unsigned short* node_p = (unsigned short*)(ws + 570368);     // 12,800,000 B
  float* coords_p        = (float*)(ws + 13370368);            //    800,000 B
  unsigned short* medge  = (unsigned short*)(ws + 14170368);   // 64,000,000 B
  float* coordw          = (float*)(ws + 78170368);            //  2,000,000 B
  int* cnt               = (int*)(ws + 80170368);              //    200,000 B
  int* adj               = (int*)(ws + 80370368);              //  9,600,000 B
  float* m_i             = (float*)(ws + 89970368);            // 12,800,000 B
  float* wr              = (float*)(ws + 102770368);           //    800,000 B

  hipMemsetAsync(cnt, 0, NN * sizeof(int), stream);
  prep_weights<<<(285184 + 255) / 256, 256, 0, stream>>>(we1, be1, we2, be2, wc1,
                                                         wn1, wn2, W1p, W2p, Wc1p,
                                                         Wn1p, Wn2p);
  prep_nodes<<<(NN * 17 + 255) / 256, 256, 0, stream>>>(x, node_p, coords_p);
  build_adj<<<(NE + 255) / 256, 256, 0, stream>>>(eidx, cnt, adj);
  edge_kernel<<<(NE + 47) / 48, 256, 0, stream>>>(node_p, coords_p, eidx, W1p, W2p,
                                                  Wc1p, bc1, bc2, wc2, medge, coordw);
  gather_kernel<<<(NN * 4 + 255) / 256, 256, 0, stream>>>(coords_p, medge, coordw,
                                                          eidx, cnt, adj, m_i, wr);
  node_mlp_kernel<<<(NN + 63) / 64, 256, 0, stream>>>(node_p, x, coords_p, m_i, wr,
                                                      Wn1p, Wn2p, bn1, bn2,
                                                      (float*)d_out);
}

// Round 13
// 528.783 us; speedup vs baseline: 1.3438x; 1.3438x over previous
//
#include <hip/hip_runtime.h>
#include <hip/hip_bf16.h>

#define NN 50000
#define NE 500000
#define DCAP 48

using bf16x8 = __attribute__((ext_vector_type(8))) short;
using f32x4  = __attribute__((ext_vector_type(4))) float;

__device__ __forceinline__ float b2f(unsigned short s) {
  union { unsigned u; float f; } v; v.u = ((unsigned)s) << 16; return v.f;
}
__device__ __forceinline__ unsigned short f2b(float f) {
  __hip_bfloat16 h = __float2bfloat16(f);
  return *reinterpret_cast<unsigned short*>(&h);
}
__device__ __forceinline__ unsigned pack2(float a, float b) {
  __hip_bfloat162 h = __float22bfloat162_rn(make_float2(a, b));
  return *reinterpret_cast<unsigned*>(&h);
}
__device__ __forceinline__ float silu_f(float x) {
  return x * __fdividef(1.f, 1.f + __expf(-x));
}

// ---------------- prep: weight repack f32 -> bf16 ----------------
// A1p[528][128]: W_e1 rows k=0..127 (dst half), K-major, n>=514 -> 0
// A2p[528][128]: W_e1 rows k=128..255 (src half)
// AdB[528]:      W_e1 row k=256 (dist row)
// W2p[64][544]:  plain K-major: k<514 = W_e2, k==514 = b_e2, else 0
// Wc1p[256][64], Wn1p[256][192], Wn2p[128][256], be1p f32[528] (pad 0)
__global__ void prep_weights(const float* __restrict__ we1,
                             const float* __restrict__ be1,
                             const float* __restrict__ we2,
                             const float* __restrict__ be2,
                             const float* __restrict__ wc1,
                             const float* __restrict__ wn1,
                             const float* __restrict__ wn2,
                             unsigned short* __restrict__ A1p,
                             unsigned short* __restrict__ A2p,
                             unsigned short* __restrict__ AdB,
                             unsigned short* __restrict__ W2p,
                             unsigned short* __restrict__ Wc1p,
                             unsigned short* __restrict__ Wn1p,
                             unsigned short* __restrict__ Wn2p,
                             float* __restrict__ be1p) {
  int i = blockIdx.x * 256 + threadIdx.x;
  if (i < 67584) {
    int n = i / 128, k = i % 128;
    A1p[i] = (n < 514) ? f2b(we1[k * 514 + n]) : (unsigned short)0;
  } else if (i < 135168) {
    int j = i - 67584; int n = j / 128, k = j % 128;
    A2p[j] = (n < 514) ? f2b(we1[(128 + k) * 514 + n]) : (unsigned short)0;
  } else if (i < 135696) {
    int j = i - 135168;
    AdB[j] = (j < 514) ? f2b(we1[256 * 514 + j]) : (unsigned short)0;
  } else if (i < 170512) {
    int j = i - 135696; int n = j / 544, lk = j % 544;
    unsigned short v = 0;
    if (lk < 514) v = f2b(we2[lk * 64 + n]);
    else if (lk == 514) v = f2b(be2[n]);
    W2p[j] = v;
  } else if (i < 186896) {
    int j = i - 170512; int n = j / 64, k = j % 64;
    Wc1p[j] = f2b(wc1[k * 256 + n]);
  } else if (i < 236048) {
    int j = i - 186896; int n = j / 192, k = j % 192;
    Wn1p[j] = f2b(wn1[k * 256 + n]);
  } else if (i < 268816) {
    int j = i - 236048; int n = j / 256, k = j % 256;
    Wn2p[j] = f2b(wn2[k * 128 + n]);
  } else if (i < 269344) {
    int j = i - 268816;
    be1p[j] = (j < 514) ? be1[j] : 0.f;
  }
}

// x(N,131) f32 -> node_p(N,128) bf16 + coords_p(N,4) f32
__global__ void prep_nodes(const float* __restrict__ x,
                           unsigned short* __restrict__ node_p,
                           float* __restrict__ coords_p) {
  int i = blockIdx.x * 256 + threadIdx.x;
  if (i < NN * 16) {
    int g = i >> 4, c = i & 15;
    const float* s = x + g * 131 + c * 8;
    unsigned short* d = node_p + g * 128 + c * 8;
#pragma unroll
    for (int j = 0; j < 8; j++) d[j] = f2b(s[j]);
  } else if (i < NN * 16 + NN) {
    int g = i - NN * 16;
    float4 c;
    c.x = x[g * 131 + 128];
    c.y = x[g * 131 + 129];
    c.z = x[g * 131 + 130];
    c.w = 0.f;
    *(float4*)(coords_p + g * 4) = c;
  }
}

// CSR-lite: per-dst edge list
__global__ void build_adj(const int* __restrict__ eidx,
                          int* __restrict__ cnt, int* __restrict__ adj) {
  int e = blockIdx.x * 256 + threadIdx.x;
  if (e < NE) {
    int d = eidx[NE + e];
    d = min(max(d, 0), NN - 1);
    int slot = atomicAdd(&cnt[d], 1);
    if (slot < DCAP) adj[d * DCAP + slot] = e;
  }
}

// ---- pgemm: P1[v] = A1*node[v] + b_e1, P2[v] = A2*node[v]  (bf16 tables) ----
__launch_bounds__(256, 2)
__global__ void pgemm_kernel(const unsigned short* __restrict__ node_p,
                             const unsigned short* __restrict__ A1p,
                             const unsigned short* __restrict__ A2p,
                             const float* __restrict__ be1p,
                             unsigned short* __restrict__ P1,
                             unsigned short* __restrict__ P2) {
  __shared__ unsigned short sNode[64][136];
  int tid = threadIdx.x, blk = blockIdx.x;
  int lane = tid & 63, wv = tid >> 6, l16 = lane & 15, quad = lane >> 4;
#pragma unroll
  for (int it = 0; it < 4; it++) {
    int t = tid + it * 256;
    int row = t >> 4, ch = t & 15;
    int g = blk * 64 + row;
    if (g >= NN) g = 0;
    *(bf16x8*)(&sNode[row][ch * 8]) = *(const bf16x8*)(node_p + g * 128 + ch * 8);
  }
  __syncthreads();
#pragma unroll 1
  for (int t = 0; t < 9; t++) {
    int T = wv + 4 * t;
    if (T >= 33) break;
    f32x4 a1[4], a2[4];
#pragma unroll
    for (int s = 0; s < 4; s++) {
      a1[s] = (f32x4){0.f, 0.f, 0.f, 0.f};
      a2[s] = (f32x4){0.f, 0.f, 0.f, 0.f};
    }
    for (int kb = 0; kb < 4; kb++) {
      bf16x8 b1 = *(const bf16x8*)(A1p + (T * 16 + l16) * 128 + kb * 32 + quad * 8);
      bf16x8 b2 = *(const bf16x8*)(A2p + (T * 16 + l16) * 128 + kb * 32 + quad * 8);
#pragma unroll
      for (int s = 0; s < 4; s++) {
        bf16x8 a = *(const bf16x8*)(&sNode[s * 16 + l16][kb * 32 + quad * 8]);
        a1[s] = __builtin_amdgcn_mfma_f32_16x16x32_bf16(b1, a, a1[s], 0, 0, 0);
        a2[s] = __builtin_amdgcn_mfma_f32_16x16x32_bf16(b2, a, a2[s], 0, 0, 0);
      }
    }
    int nb = T * 16 + quad * 4;
    float4 b4 = *(const float4*)(be1p + nb);
    bool v0 = nb + 0 < 514, v1 = nb + 1 < 514, v2 = nb + 2 < 514, v3 = nb + 3 < 514;
#pragma unroll
    for (int s = 0; s < 4; s++) {
      int g = blk * 64 + s * 16 + l16;
      if (g < NN) {
        float p0 = v0 ? a1[s][0] + b4.x : 0.f;
        float p1v = v1 ? a1[s][1] + b4.y : 0.f;
        float p2v = v2 ? a1[s][2] + b4.z : 0.f;
        float p3 = v3 ? a1[s][3] + b4.w : 0.f;
        *(uint2*)(P1 + g * 528 + nb) = make_uint2(pack2(p0, p1v), pack2(p2v, p3));
        float q0 = v0 ? a2[s][0] : 0.f;
        float q1 = v1 ? a2[s][1] : 0.f;
        float q2 = v2 ? a2[s][2] : 0.f;
        float q3 = v3 ? a2[s][3] : 0.f;
        *(uint2*)(P2 + g * 528 + nb) = make_uint2(pack2(q0, q1), pack2(q2, q3));
      }
    }
  }
}

// ---- edge kernel v2: linearity — combine P1[dst]+P2[src]+dist*Ad, silu,
// then layer2 MFMA + coord head. 48 edges/block, 4x128 K-chunks, ~25 KB LDS.
__launch_bounds__(256, 3)
__global__ void edge_kernel(const unsigned short* __restrict__ P1,
                            const unsigned short* __restrict__ P2,
                            const unsigned short* __restrict__ AdB,
                            const float* __restrict__ coords_p,
                            const int* __restrict__ eidx,
                            const unsigned short* __restrict__ W2p,
                            const unsigned short* __restrict__ Wc1p,
                            const float* __restrict__ bc1,
                            const float* __restrict__ bc2,
                            const float* __restrict__ wc2,
                            unsigned short* __restrict__ medge,
                            float* __restrict__ coordw) {
  __shared__ unsigned short sHc[48][168];   // 16,128 B (ch3: 160 cols)
  __shared__ unsigned short sM[48][72];     //  6,912 B
  __shared__ int sDst[48];
  __shared__ int sSrc[48];
  __shared__ float sDistF[48];
  __shared__ float sCwPart[4][48];
  int tid = threadIdx.x, blk = blockIdx.x;
  int lane = tid & 63, wv = tid >> 6, l16 = lane & 15, quad = lane >> 4;

  if (tid < 48) {
    int e = min(blk * 48 + tid, NE - 1);
    int s = eidx[e], d = eidx[NE + e];
    s = min(max(s, 0), NN - 1);
    d = min(max(d, 0), NN - 1);
    float4 cs = *(const float4*)(coords_p + s * 4);
    float4 cd = *(const float4*)(coords_p + d * 4);
    float rx = cs.x - cd.x, ry = cs.y - cd.y, rz = cs.z - cd.z;
    sDst[tid] = d;
    sSrc[tid] = s;
    sDistF[tid] = sqrtf(rx * rx + ry * ry + rz * rz);
  }
  __syncthreads();

  f32x4 macc[3];
#pragma unroll
  for (int s = 0; s < 3; s++) macc[s] = (f32x4){0.f, 0.f, 0.f, 0.f};

#pragma unroll 1
  for (int ch = 0; ch < 4; ch++) {
    // ---- combine: h[col] = silu(P1[dst][col] + P2[src][col] + dist*Ad[col])
#pragma unroll
    for (int it = 0; it < 3; it++) {
      int u = tid + it * 256;               // 768 = 48 edges x 16 col-groups
      int edge = u >> 4, cg = u & 15;
      int col = ch * 128 + cg * 8;
      bf16x8 v1 = *(const bf16x8*)(P1 + sDst[edge] * 528 + col);
      bf16x8 v2 = *(const bf16x8*)(P2 + sSrc[edge] * 528 + col);
      bf16x8 va = *(const bf16x8*)(AdB + col);
      float dist = sDistF[edge];
      float h0 = silu_f(b2f((unsigned short)v1[0]) + b2f((unsigned short)v2[0]) + dist * b2f((unsigned short)va[0]));
      float h1 = silu_f(b2f((unsigned short)v1[1]) + b2f((unsigned short)v2[1]) + dist * b2f((unsigned short)va[1]));
      float h2 = silu_f(b2f((unsigned short)v1[2]) + b2f((unsigned short)v2[2]) + dist * b2f((unsigned short)va[2]));
      float h3 = silu_f(b2f((unsigned short)v1[3]) + b2f((unsigned short)v2[3]) + dist * b2f((unsigned short)va[3]));
      float h4 = silu_f(b2f((unsigned short)v1[4]) + b2f((unsigned short)v2[4]) + dist * b2f((unsigned short)va[4]));
      float h5 = silu_f(b2f((unsigned short)v1[5]) + b2f((unsigned short)v2[5]) + dist * b2f((unsigned short)va[5]));
      float h6 = silu_f(b2f((unsigned short)v1[6]) + b2f((unsigned short)v2[6]) + dist * b2f((unsigned short)va[6]));
      float h7 = silu_f(b2f((unsigned short)v1[7]) + b2f((unsigned short)v2[7]) + dist * b2f((unsigned short)va[7]));
      *(uint4*)(&sHc[edge][cg * 8]) =
          make_uint4(pack2(h0, h1), pack2(h2, h3), pack2(h4, h5), pack2(h6, h7));
    }
    if (ch == 3 && tid < 48) {  // tail: h[512], h[513], bias-one, zeros
      int edge = tid;
      float dist = sDistF[edge];
      int bd = sDst[edge] * 528, bs = sSrc[edge] * 528;
      float h512 = silu_f(b2f(P1[bd + 512]) + b2f(P2[bs + 512]) + dist * b2f(AdB[512]));
      float h513 = silu_f(b2f(P1[bd + 513]) + b2f(P2[bs + 513]) + dist * b2f(AdB[513]));
      *(uint4*)(&sHc[edge][128]) = make_uint4(pack2(h512, h513), pack2(1.0f, 0.f), 0u, 0u);
      *(uint4*)(&sHc[edge][144]) = make_uint4(0u, 0u, 0u, 0u);
    }
    __syncthreads();
    // ---- layer2 partial: m += h_chunk @ W2 (k = ch*128 + local) ----
    int nkb = (ch == 3) ? 5 : 4;
    for (int kb = 0; kb < nkb; kb++) {
      bf16x8 b = *(const bf16x8*)(W2p + (wv * 16 + l16) * 544 + ch * 128 + kb * 32 + quad * 8);
#pragma unroll
      for (int s = 0; s < 3; s++) {
        bf16x8 a = *(const bf16x8*)(&sHc[s * 16 + l16][kb * 32 + quad * 8]);
        macc[s] = __builtin_amdgcn_mfma_f32_16x16x32_bf16(b, a, macc[s], 0, 0, 0);
      }
    }
    __syncthreads();
  }

  // ---- m_ij = silu(macc) -> sM ----
  {
    int nb = wv * 16 + quad * 4;
#pragma unroll
    for (int s = 0; s < 3; s++) {
      unsigned lo = pack2(silu_f(macc[s][0]), silu_f(macc[s][1]));
      unsigned hi = pack2(silu_f(macc[s][2]), silu_f(macc[s][3]));
      *(uint2*)(&sM[s * 16 + l16][nb]) = make_uint2(lo, hi);
    }
  }
  __syncthreads();

  // ---- coord head: cw = silu(m @ W_c1 + b_c1) @ W_c2 ----
  {
    float cw[3] = {0.f, 0.f, 0.f};
#pragma unroll
    for (int jt = 0; jt < 4; jt++) {
      int T = wv * 4 + jt;
      f32x4 cacc[3];
#pragma unroll
      for (int s = 0; s < 3; s++) cacc[s] = (f32x4){0.f, 0.f, 0.f, 0.f};
#pragma unroll
      for (int kb = 0; kb < 2; kb++) {
        bf16x8 b = *(const bf16x8*)(Wc1p + (T * 16 + l16) * 64 + kb * 32 + quad * 8);
#pragma unroll
        for (int s = 0; s < 3; s++) {
          bf16x8 a = *(const bf16x8*)(&sM[s * 16 + l16][kb * 32 + quad * 8]);
          cacc[s] = __builtin_amdgcn_mfma_f32_16x16x32_bf16(b, a, cacc[s], 0, 0, 0);
        }
      }
      int nb = T * 16 + quad * 4;
      float4 b4 = *(const float4*)(bc1 + nb);
      float4 w4 = *(const float4*)(wc2 + nb);
#pragma unroll
      for (int s = 0; s < 3; s++) {
        cw[s] += silu_f(cacc[s][0] + b4.x) * w4.x;
        cw[s] += silu_f(cacc[s][1] + b4.y) * w4.y;
        cw[s] += silu_f(cacc[s][2] + b4.z) * w4.z;
        cw[s] += silu_f(cacc[s][3] + b4.w) * w4.w;
      }
    }
#pragma unroll
    for (int s = 0; s < 3; s++) {
      cw[s] += __shfl_xor(cw[s], 16, 64);
      cw[s] += __shfl_xor(cw[s], 32, 64);
    }
    if (quad == 0) {
#pragma unroll
      for (int s = 0; s < 3; s++) sCwPart[wv][s * 16 + l16] = cw[s];
    }
  }
  __syncthreads();
  // ---- stores ----
#pragma unroll
  for (int it = 0; it < 2; it++) {
    int idx = it * 256 + tid;
    if (idx < 384) {
      int row = idx >> 3, ch8 = idx & 7;
      int e = blk * 48 + row;
      if (e < NE)
        *(bf16x8*)(medge + (size_t)e * 64 + ch8 * 8) = *(const bf16x8*)(&sM[row][ch8 * 8]);
    }
  }
  if (tid < 48) {
    int e = blk * 48 + tid;
    if (e < NE) {
      float v = sCwPart[0][tid] + sCwPart[1][tid] + sCwPart[2][tid] + sCwPart[3][tid]
                + bc2[0];
      coordw[e] = v;
    }
  }
}

// ---- gather kernel: LDS-free, 4 lanes/node ----
__global__ void gather_kernel(const float* __restrict__ coords_p,
                              const unsigned short* __restrict__ medge,
                              const float* __restrict__ coordw,
                              const int* __restrict__ eidx,
                              const int* __restrict__ cnt,
                              const int* __restrict__ adj,
                              float* __restrict__ m_i,
                              float* __restrict__ wr) {
  int t = blockIdx.x * 256 + threadIdx.x;
  int g = t >> 2, c = t & 3;
  if (g >= NN) return;
  int deg = min(cnt[g], DCAP);
  float acc[16];
#pragma unroll
  for (int i = 0; i < 16; i++) acc[i] = 0.f;
  float sc = 0.f;
  float cg = (c < 3) ? coords_p[g * 4 + c] : 0.f;
  for (int k = 0; k < deg; k++) {
    int e = adj[g * DCAP + k];
    const unsigned short* mrow = medge + (size_t)e * 64 + c * 16;
    bf16x8 a0 = *(const bf16x8*)(mrow);
    bf16x8 a1 = *(const bf16x8*)(mrow + 8);
#pragma unroll
    for (int i = 0; i < 8; i++) acc[i] += b2f((unsigned short)a0[i]);
#pragma unroll
    for (int i = 0; i < 8; i++) acc[8 + i] += b2f((unsigned short)a1[i]);
    if (c == 3) {
      sc += coordw[e];
    } else {
      int s = eidx[e];
      s = min(max(s, 0), NN - 1);
      sc += coords_p[s * 4 + c] - cg;
    }
  }
  float4* dst = (float4*)(m_i + g * 64 + c * 16);
  dst[0] = make_float4(acc[0], acc[1], acc[2], acc[3]);
  dst[1] = make_float4(acc[4], acc[5], acc[6], acc[7]);
  dst[2] = make_float4(acc[8], acc[9], acc[10], acc[11]);
  dst[3] = make_float4(acc[12], acc[13], acc[14], acc[15]);
  wr[g * 4 + c] = sc;
}

// ---------------- node MLP kernel: pure GEMM, f32 output -------------------
__launch_bounds__(256, 2)
__global__ void node_mlp_kernel(const unsigned short* __restrict__ node_p,
                                const float* __restrict__ x,
                                const float* __restrict__ coords_p,
                                const float* __restrict__ m_i,
                                const float* __restrict__ wr,
                                const unsigned short* __restrict__ Wn1p,
                                const unsigned short* __restrict__ Wn2p,
                                const float* __restrict__ bn1,
                                const float* __restrict__ bn2,
                                float* __restrict__ out) {
  __shared__ unsigned short sNin[64][200];
  __shared__ unsigned short sHid[64][264];
  int tid = threadIdx.x, blk = blockIdx.x;
  int lane = tid & 63, wv = tid >> 6, l16 = lane & 15, quad = lane >> 4;

#pragma unroll
  for (int it = 0; it < 4; it++) {
    int t = tid + it * 256;
    int row = t >> 4, ch = t & 15;
    int g = blk * 64 + row;
    if (g >= NN) g = 0;
    *(bf16x8*)(&sNin[row][ch * 8]) = *(const bf16x8*)(node_p + g * 128 + ch * 8);
  }
#pragma unroll
  for (int it = 0; it < 2; it++) {
    int t = tid + it * 256;
    int row = t >> 3, q = t & 7;
    int g = blk * 64 + row;
    if (g >= NN) g = 0;
    float4 v1 = *(const float4*)(m_i + g * 64 + q * 8);
    float4 v2 = *(const float4*)(m_i + g * 64 + q * 8 + 4);
    *(uint2*)(&sNin[row][128 + q * 8]) = make_uint2(pack2(v1.x, v1.y), pack2(v1.z, v1.w));
    *(uint2*)(&sNin[row][128 + q * 8 + 4]) = make_uint2(pack2(v2.x, v2.y), pack2(v2.z, v2.w));
  }
  __syncthreads();
  {
    f32x4 acc[4][4];
#pragma unroll
    for (int j = 0; j < 4; j++)
#pragma unroll
      for (int s = 0; s < 4; s++) acc[j][s] = (f32x4){0.f, 0.f, 0.f, 0.f};
    for (int kb = 0; kb < 6; kb++) {
      bf16x8 afr[4], bfr[4];
#pragma unroll
      for (int s = 0; s < 4; s++)
        afr[s] = *(const bf16x8*)(&sNin[s * 16 + l16][kb * 32 + quad * 8]);
#pragma unroll
      for (int j = 0; j < 4; j++)
        bfr[j] = *(const bf16x8*)(Wn1p + ((wv * 4 + j) * 16 + l16) * 192 + kb * 32 + quad * 8);
#pragma unroll
      for (int j = 0; j < 4; j++)
#pragma unroll
        for (int s = 0; s < 4; s++)
          acc[j][s] = __builtin_amdgcn_mfma_f32_16x16x32_bf16(bfr[j], afr[s], acc[j][s], 0, 0, 0);
    }
#pragma unroll
    for (int j = 0; j < 4; j++) {
      int nb = (wv * 4 + j) * 16 + quad * 4;
      float4 b4 = *(const float4*)(bn1 + nb);
#pragma unroll
      for (int s = 0; s < 4; s++) {
        unsigned lo = pack2(silu_f(acc[j][s][0] + b4.x), silu_f(acc[j][s][1] + b4.y));
        unsigned hi = pack2(silu_f(acc[j][s][2] + b4.z), silu_f(acc[j][s][3] + b4.w));
        *(uint2*)(&sHid[s * 16 + l16][nb]) = make_uint2(lo, hi);
      }
    }
  }
  __syncthreads();
  {
    f32x4 acc[2][4];
#pragma unroll
    for (int j = 0; j < 2; j++)
#pragma unroll
      for (int s = 0; s < 4; s++) acc[j][s] = (f32x4){0.f, 0.f, 0.f, 0.f};
    for (int kb = 0; kb < 8; kb++) {
      bf16x8 afr[4], bfr[2];
#pragma unroll
      for (int s = 0; s < 4; s++)
        afr[s] = *(const bf16x8*)(&sHid[s * 16 + l16][kb * 32 + quad * 8]);
#pragma unroll
      for (int j = 0; j < 2; j++)
        bfr[j] = *(const bf16x8*)(Wn2p + ((wv * 2 + j) * 16 + l16) * 256 + kb * 32 + quad * 8);
#pragma unroll
      for (int j = 0; j < 2; j++)
#pragma unroll
        for (int s = 0; s < 4; s++)
          acc[j][s] = __builtin_amdgcn_mfma_f32_16x16x32_bf16(bfr[j], afr[s], acc[j][s], 0, 0, 0);
    }
#pragma unroll
    for (int j = 0; j < 2; j++) {
      int nb = (wv * 2 + j) * 16 + quad * 4;
      float4 b4 = *(const float4*)(bn2 + nb);
#pragma unroll
      for (int s = 0; s < 4; s++) {
        int g = blk * 64 + s * 16 + l16;
        if (g < NN) {
          int base = g * 131 + nb;
          out[base + 0] = acc[j][s][0] + b4.x + x[base + 0];
          out[base + 1] = acc[j][s][1] + b4.y + x[base + 1];
          out[base + 2] = acc[j][s][2] + b4.z + x[base + 2];
          out[base + 3] = acc[j][s][3] + b4.w + x[base + 3];
        }
      }
    }
  }
  if (tid < 64) {
    int g = blk * 64 + tid;
    if (g < NN) {
      float4 w4 = *(const float4*)(wr + g * 4);
      out[g * 131 + 128] = coords_p[g * 4 + 0] + w4.w * w4.x;
      out[g * 131 + 129] = coords_p[g * 4 + 1] + w4.w * w4.y;
      out[g * 131 + 130] = coords_p[g * 4 + 2] + w4.w * w4.z;
    }
  }
}

extern "C" void kernel_launch(void* const* d_in, const int* in_sizes, int n_in,
                              void* d_out, int out_size, void* d_ws, size_t ws_size,
                              hipStream_t stream) {
  const float* x   = (const float*)d_in[0];
  const int* eidx  = (const int*)d_in[1];
  const float* we1 = (const float*)d_in[2];
  const float* be1 = (const float*)d_in[3];
  const float* we2 = (const float*)d_in[4];
  const float* be2 = (const float*)d_in[5];
  const float* wc1 = (const float*)d_in[6];
  const float* bc1 = (const float*)d_in[7];
  const float* wc2 = (const float*)d_in[8];
  const float* bc2 = (const float*)d_in[9];
  const float* wn1 = (const float*)d_in[10];
  const float* bn1 = (const float*)d_in[11];
  const float* wn2 = (const float*)d_in[12];
  const float* bn2 = (const float*)d_in[13];

  char* ws = (char*)d_ws;
  unsigned short* A1p    = (unsigned short*)(ws + 0);          //    135,168 B
  unsigned short* A2p    = (unsigned short*)(ws + 135168);     //    135,168 B
  unsigned short* AdB    = (unsigned short*)(ws + 270336);     //      1,056 B
  unsigned short* W2p    = (unsigned short*)(ws + 271392);     //     69,632 B
  unsigned short* Wc1p   = (unsigned short*)(ws + 341024);     //     32,768 B
  unsigned short* Wn1p   = (unsigned short*)(ws + 373792);     //     98,304 B
  unsigned short* Wn2p   = (unsigned short*)(ws + 472096);     //     65,536 B
  float* be1p            = (float*)(ws + 537632);              //      2,112 B
  unsigned short* node_p = (unsigned short*)(ws + 539744);     // 12,800,000 B
  float* coords_p        = (float*)(ws + 13339744);            //    800,000 B
  unsigned short* medge  = (unsigned short*)(ws + 14139744);   // 64,000,000 B
  float* coordw          = (float*)(ws + 78139744);            //  2,000,000 B
  int* cnt               = (int*)(ws + 80139744);              //    200,000 B
  int* adj               = (int*)(ws + 80339744);              //  9,600,000 B
  float* m_i             = (float*)(ws + 89939744);            // 12,800,000 B
  float* wr              = (float*)(ws + 102739744);           //    800,000 B
  unsigned short* P1     = (unsigned short*)(ws + 103539744);  // 52,800,000 B
  unsigned short* P2     = (unsigned short*)(ws + 156339744);  // 52,800,000 B

  hipMemsetAsync(cnt, 0, NN * sizeof(int), stream);
  prep_weights<<<(269344 + 255) / 256, 256, 0, stream>>>(we1, be1, we2, be2, wc1,
                                                         wn1, wn2, A1p, A2p, AdB,
                                                         W2p, Wc1p, Wn1p, Wn2p, be1p);
  prep_nodes<<<(NN * 17 + 255) / 256, 256, 0, stream>>>(x, node_p, coords_p);
  pgemm_kernel<<<(NN + 63) / 64, 256, 0, stream>>>(node_p, A1p, A2p, be1p, P1, P2);
  build_adj<<<(NE + 255) / 256, 256, 0, stream>>>(eidx, cnt, adj);
  edge_kernel<<<(NE + 47) / 48, 256, 0, stream>>>(P1, P2, AdB, coords_p, eidx,
                                                  W2p, Wc1p, bc1, bc2, wc2,
                                                  medge, coordw);
  gather_kernel<<<(NN * 4 + 255) / 256, 256, 0, stream>>>(coords_p, medge, coordw,
                                                          eidx, cnt, adj, m_i, wr);
  node_mlp_kernel<<<(NN + 63) / 64, 256, 0, stream>>>(node_p, x, coords_p, m_i, wr,
                                                      Wn1p, Wn2p, bn1, bn2,
                                                      (float*)d_out);
}